// Round 7
// baseline (141.765 us; speedup 1.0000x reference)
//
#include <hip/hip_runtime.h>
#include <hip/hip_bf16.h>

typedef __hip_bfloat16 bf16;
typedef __bf16 bf16x8 __attribute__((ext_vector_type(8)));
typedef float f32x4 __attribute__((ext_vector_type(4)));
typedef unsigned short u16x8 __attribute__((ext_vector_type(8)));

#define B_SZ   4
#define T_SEQ  2048
#define D_IN   1024
#define D_QKV  64
#define BT     (B_SZ * T_SEQ)   // 8192 rows
#define PSTR   72               // attn p-tile LDS row stride (+8 pad, 16B rows)
#define KSPL   8                // attention K-split ways (waves per block)

// ---------------------------------------------------------------------------
// Kernel 0: W transpose/convert via LDS, coalesced. 48 blocks: 16 per matrix,
// each handles 64 k-rows. Wt[n][k] bf16, n = 0..191 over [Wq|Wk|Wv].
// ---------------------------------------------------------------------------
__global__ __launch_bounds__(256) void wt_prep(
    const float* __restrict__ Wq, const float* __restrict__ Wk,
    const float* __restrict__ Wv, bf16* __restrict__ wt)
{
    __shared__ float ws[64 * 65];
    const int bx = blockIdx.x;
    const int m  = bx >> 4;
    const int k0 = (bx & 15) << 6;
    const float* W = (m == 0) ? Wq : (m == 1) ? Wk : Wv;
    const int tid = threadIdx.x;
    #pragma unroll
    for (int i = 0; i < 16; ++i) {
        const int idx = i * 256 + tid;          // coalesced over n
        const int kk = idx >> 6, nn = idx & 63;
        ws[kk * 65 + nn] = W[(size_t)(k0 + kk) * D_QKV + nn];
    }
    __syncthreads();
    const int n = tid >> 2, kq = (tid & 3) << 4;
    bf16 tmp[16];
    #pragma unroll
    for (int j = 0; j < 16; ++j)
        tmp[j] = __float2bfloat16(ws[(kq + j) * 65 + n]);
    uint4* dst = (uint4*)(wt + (size_t)(m * 64 + n) * D_IN + k0 + kq);
    dst[0] = ((uint4*)tmp)[0];
    dst[1] = ((uint4*)tmp)[1];
}

// ---------------------------------------------------------------------------
// Kernel A: QKV projection MFMA GEMM, register-pipelined with sched_barrier
// to keep loads hoisted. 512 blocks x 4 waves; block owns 16 x-rows; wave
// owns 3 n-tiles. K=64/iter; A (HBM) prefetch distance 2, B (L1) distance 1.
// __launch_bounds__(256,2): VGPR cap 256 so the ring buffers survive.
// ---------------------------------------------------------------------------
__global__ __launch_bounds__(256, 2) void qkv_proj_mfma(
    const float* __restrict__ x, const bf16* __restrict__ wt,
    bf16* __restrict__ qb, bf16* __restrict__ kb, bf16* __restrict__ vt)
{
    const int tid  = threadIdx.x;
    const int wave = tid >> 6;
    const int lane = tid & 63;
    const int col  = lane & 15;
    const int quad = lane >> 4;
    const size_t rowbase = (size_t)blockIdx.x * 16;
    const int nt0 = wave * 3;

    const float4* xr  = (const float4*)(x + (rowbase + col) * D_IN);  // 256 f4/row
    const uint4*  wt4 = (const uint4*)wt;                             // 128 u4/n-row

    f32x4 acc[3];
    #pragma unroll
    for (int i = 0; i < 3; ++i) acc[i] = (f32x4){0.f, 0.f, 0.f, 0.f};

    float4 a[3][4];   // A ring, distance-2 prefetch
    uint4  b[2][6];   // B ring, distance-1 prefetch

    // prologue: A iters 0,1; B iter 0
    #pragma unroll
    for (int p = 0; p < 2; ++p)
        #pragma unroll
        for (int h = 0; h < 2; ++h) {
            a[p][h * 2]     = xr[p * 16 + h * 8 + quad * 2];
            a[p][h * 2 + 1] = xr[p * 16 + h * 8 + quad * 2 + 1];
        }
    #pragma unroll
    for (int i = 0; i < 3; ++i) {
        const size_t n = (size_t)((nt0 + i) * 16 + col) * 128;
        b[0][i * 2]     = wt4[n + quad];
        b[0][i * 2 + 1] = wt4[n + 4 + quad];
    }

    #pragma unroll
    for (int it = 0; it < 16; ++it) {
        if (it + 2 < 16) {                    // prefetch A for iter it+2
            const int kofs = (it + 2) * 16;
            #pragma unroll
            for (int h = 0; h < 2; ++h) {
                a[(it + 2) % 3][h * 2]     = xr[kofs + h * 8 + quad * 2];
                a[(it + 2) % 3][h * 2 + 1] = xr[kofs + h * 8 + quad * 2 + 1];
            }
        }
        if (it + 1 < 16) {                    // prefetch B for iter it+1
            #pragma unroll
            for (int i = 0; i < 3; ++i) {
                const size_t n = (size_t)((nt0 + i) * 16 + col) * 128 + (it + 1) * 8;
                b[(it + 1) & 1][i * 2]     = wt4[n + quad];
                b[(it + 1) & 1][i * 2 + 1] = wt4[n + 4 + quad];
            }
        }
        __builtin_amdgcn_sched_barrier(0);    // don't sink the prefetches
        #pragma unroll
        for (int h = 0; h < 2; ++h) {
            const float4 a0 = a[it % 3][h * 2], a1 = a[it % 3][h * 2 + 1];
            const bf16x8 af = (bf16x8){(__bf16)a0.x, (__bf16)a0.y, (__bf16)a0.z, (__bf16)a0.w,
                                       (__bf16)a1.x, (__bf16)a1.y, (__bf16)a1.z, (__bf16)a1.w};
            #pragma unroll
            for (int i = 0; i < 3; ++i)
                acc[i] = __builtin_amdgcn_mfma_f32_16x16x32_bf16(
                             af, __builtin_bit_cast(bf16x8, b[it & 1][i * 2 + h]), acc[i], 0, 0, 0);
        }
    }

    // epilogue: q/k row-major, v transposed
    const int bb = (int)(rowbase >> 11);
    const int t0 = (int)(rowbase & (T_SEQ - 1));
    #pragma unroll
    for (int i = 0; i < 3; ++i) {
        const int ntile = nt0 + i;
        const int n = ntile * 16 + col;
        if (ntile < 4) {
            #pragma unroll
            for (int r = 0; r < 4; ++r)
                qb[(rowbase + quad * 4 + r) * D_QKV + n] = __float2bfloat16(acc[i][r]);
        } else if (ntile < 8) {
            #pragma unroll
            for (int r = 0; r < 4; ++r)
                kb[(rowbase + quad * 4 + r) * D_QKV + (n - 64)] = __float2bfloat16(acc[i][r]);
        } else {
            #pragma unroll
            for (int r = 0; r < 4; ++r)
                vt[(size_t)bb * D_QKV * T_SEQ + (size_t)(n - 128) * T_SEQ + t0 + quad * 4 + r] =
                    __float2bfloat16(acc[i][r]);
        }
    }
}

// ---------------------------------------------------------------------------
// Kernel B: MFMA flash attention, no-max softmax (scores bounded), 8-way
// K-split per 512-thread block: wave w takes chunks c%8==w, linear combine
// in LDS. 512 blocks x 8 waves = 16 waves/CU.
// ---------------------------------------------------------------------------
__global__ __launch_bounds__(512, 4) void attn_kernel(
    const bf16* __restrict__ qb, const bf16* __restrict__ kb,
    const bf16* __restrict__ vt, float* __restrict__ out)
{
    __shared__ unsigned short plds[KSPL * 16 * PSTR];  // 18 KB per-wave P tiles
    __shared__ float os[KSPL][16][64];                 // 32 KB per-wave O
    __shared__ float lw[KSPL][16];                     // per-wave l

    const int tid  = threadIdx.x;
    const int wave = tid >> 6;
    const int lane = tid & 63;
    const int col  = lane & 15;
    const int quad = lane >> 4;
    const int tl   = blockIdx.x;
    const int b    = tl >> 7;
    const int qw   = (127 - (tl & 127)) << 4;          // heavy tiles first
    const int nch  = (qw >> 6) + 1;

    const uint4* q4 = (const uint4*)(qb + (size_t)b * T_SEQ * D_QKV);
    const uint4* k4 = (const uint4*)(kb + (size_t)b * T_SEQ * D_QKV);
    const uint4* v4 = (const uint4*)(vt + (size_t)b * D_QKV * T_SEQ);

    const bf16x8 aq0 = __builtin_bit_cast(bf16x8, q4[(qw + col) * 8 + quad]);
    const bf16x8 aq1 = __builtin_bit_cast(bf16x8, q4[(qw + col) * 8 + 4 + quad]);

    f32x4 o[4];
    float ls[4];
    #pragma unroll
    for (int dt = 0; dt < 4; ++dt) o[dt] = (f32x4){0.f, 0.f, 0.f, 0.f};
    #pragma unroll
    for (int r = 0; r < 4; ++r) ls[r] = 0.f;

    unsigned short* pl = plds + wave * 16 * PSTR;
    const u16x8* p8 = (const u16x8*)pl;

    for (int c = wave; c < nch; c += KSPL) {
        const int kbase = c << 6;

        // V for this chunk (issued early, consumed after softmax)
        bf16x8 bv0[4], bv1[4];
        #pragma unroll
        for (int dt = 0; dt < 4; ++dt) {
            bv0[dt] = __builtin_bit_cast(bf16x8, v4[(dt * 16 + col) * 256 + (kbase >> 3) + quad]);
            bv1[dt] = __builtin_bit_cast(bf16x8, v4[(dt * 16 + col) * 256 + (kbase >> 3) + 4 + quad]);
        }

        // QK^T
        f32x4 sc[4];
        #pragma unroll
        for (int nt = 0; nt < 4; ++nt) {
            const int krow = kbase + nt * 16 + col;
            const bf16x8 bk0 = __builtin_bit_cast(bf16x8, k4[krow * 8 + quad]);
            const bf16x8 bk1 = __builtin_bit_cast(bf16x8, k4[krow * 8 + 4 + quad]);
            sc[nt] = (f32x4){0.f, 0.f, 0.f, 0.f};
            sc[nt] = __builtin_amdgcn_mfma_f32_16x16x32_bf16(aq0, bk0, sc[nt], 0, 0, 0);
            sc[nt] = __builtin_amdgcn_mfma_f32_16x16x32_bf16(aq1, bk1, sc[nt], 0, 0, 0);
        }

        // causal mask (only the final chunk can contain k > q)
        if (c == nch - 1) {
            #pragma unroll
            for (int nt = 0; nt < 4; ++nt) {
                const int kp = kbase + nt * 16 + col;
                #pragma unroll
                for (int r = 0; r < 4; ++r)
                    if (kp > qw + quad * 4 + r) sc[nt][r] = -INFINITY;
            }
        }

        // P = exp(s/8) raw (no max subtraction); per-lane l accumulation
        #pragma unroll
        for (int nt = 0; nt < 4; ++nt) {
            #pragma unroll
            for (int r = 0; r < 4; ++r) {
                const float pv = __expf(sc[nt][r] * 0.125f);
                ls[r] += pv;
                pl[(quad * 4 + r) * PSTR + nt * 16 + col] =
                    __builtin_bit_cast(unsigned short, __float2bfloat16(pv));
            }
        }

        // P A-fragments from LDS (same-wave RAW; lgkmcnt handles it)
        const bf16x8 pa0 = __builtin_bit_cast(bf16x8, p8[col * 9 + quad]);
        const bf16x8 pa1 = __builtin_bit_cast(bf16x8, p8[col * 9 + 4 + quad]);

        // O += P * V
        #pragma unroll
        for (int dt = 0; dt < 4; ++dt) {
            o[dt] = __builtin_amdgcn_mfma_f32_16x16x32_bf16(pa0, bv0[dt], o[dt], 0, 0, 0);
            o[dt] = __builtin_amdgcn_mfma_f32_16x16x32_bf16(pa1, bv1[dt], o[dt], 0, 0, 0);
        }
    }

    // single post-loop l reduction over the 16 key-lanes
    #pragma unroll
    for (int r = 0; r < 4; ++r) {
        #pragma unroll
        for (int msk = 1; msk < 16; msk <<= 1)
            ls[r] += __shfl_xor(ls[r], msk);
    }
    if (col == 0) {
        #pragma unroll
        for (int r = 0; r < 4; ++r) lw[wave][quad * 4 + r] = ls[r];
    }
    #pragma unroll
    for (int dt = 0; dt < 4; ++dt)
        #pragma unroll
        for (int r = 0; r < 4; ++r)
            os[wave][quad * 4 + r][dt * 16 + col] = o[dt][r];
    __syncthreads();

    // combine KSPL partial (O, l) and store
    #pragma unroll
    for (int i = 0; i < 2; ++i) {
        const int idx = i * 512 + tid;
        const int q = idx >> 6, d = idx & 63;
        float s = 0.f, l = 0.f;
        #pragma unroll
        for (int w = 0; w < KSPL; ++w) { s += os[w][q][d]; l += lw[w][q]; }
        out[((size_t)b * T_SEQ + qw + q) * D_QKV + d] = s / l;
    }
}

// ---------------------------------------------------------------------------
extern "C" void kernel_launch(void* const* d_in, const int* in_sizes, int n_in,
                              void* d_out, int out_size, void* d_ws, size_t ws_size,
                              hipStream_t stream) {
    const float* x  = (const float*)d_in[0];
    const float* Wq = (const float*)d_in[1];
    const float* Wk = (const float*)d_in[2];
    const float* Wv = (const float*)d_in[3];
    float* out = (float*)d_out;

    bf16* qb = (bf16*)d_ws;                       // 1 MB
    bf16* kb = qb + (size_t)BT * D_QKV;           // 1 MB
    bf16* vt = kb + (size_t)BT * D_QKV;           // 1 MB
    bf16* wt = vt + (size_t)BT * D_QKV;           // 384 KB

    wt_prep<<<48, 256, 0, stream>>>(Wq, Wk, Wv, wt);
    qkv_proj_mfma<<<BT / 16, 256, 0, stream>>>(x, wt, qb, kb, vt);
    attn_kernel<<<BT / 16, 512, 0, stream>>>(qb, kb, vt, out);
}